// Round 18
// baseline (20.313 us; speedup 1.0000x reference)
//
#include <hip/hip_runtime.h>
#include <hip/hip_fp16.h>

#define OUTF 11008
#define INF  4096
#define NBLK 344   // 32 o-rows per block

typedef unsigned int uint;
typedef __attribute__((ext_vector_type(8))) _Float16 f16x8;  // MFMA A/B (4 VGPR)
typedef __attribute__((ext_vector_type(4))) float f32x4;     // MFMA C/D

typedef __attribute__((address_space(1))) void gvoid_t;
typedef __attribute__((address_space(3))) void svoid_t;

union UA { uint4 u4; uint u[4]; f16x8 v; };
union UH { uint u; __half2 h; };
union USH { unsigned short s; __half h; };

#define WAITV(n) asm volatile("s_waitcnt vmcnt(" #n ")" ::: "memory")
#define FENCE()  asm volatile("" ::: "memory")
#define BARRIER() { FENCE(); __builtin_amdgcn_s_barrier(); FENCE(); }

// Single kernel. Block = 512 thr = 8 waves, one 32-row o-tile, 16 block-global
// K-chunks of 256k. Wave (kq=wv>>1, oh=wv&1): groups {kq*2,+2} of each chunk
// for o-half oh. X staged block-shared (serves all 32 rows); W per-row-slice.
__global__ __launch_bounds__(512, 4) void lin2bit_kernel(
    const float* __restrict__ x, const int* __restrict__ wq,
    const float* __restrict__ wn, const float* __restrict__ bias,
    float* __restrict__ out)
{
  // LUT 2048 | NL 16384 | X0 16384 | X1 16384 | W0 8192 | W1 8192 = 67584
  __shared__ __align__(16) char lds[67584];
  char* LUT = lds;
  char* NL  = lds + 2048;
  char* X0  = lds + 18432;
  char* X1  = lds + 34816;
  char* W0  = lds + 51200;
  char* W1  = lds + 59392;

  const int tid = threadIdx.x;
  const int wv  = tid >> 6;          // 0..7
  const int kq  = wv >> 1;           // group-slice of each chunk (0..3)
  const int oh  = wv & 1;            // o-half (0..1)
  const int l   = tid & 63;
  const int col = l & 15;            // A-row (m) / B-col within 16-col sub-tile
  const int q   = l >> 4;            // lane covers k = 8q..8q+7 of each group
  const int o0  = (int)blockIdx.x << 5;

  const char* xb  = (const char*)x;
  const char* wqb = (const char*)wq;
  const char* wnb = (const char*)wn;

  // ---- norms DMA once: 32 rows x 512B, 16 instr (2/wave); 16B-granule swizzle r&7
  {
#pragma unroll
    for (int ii = 0; ii < 2; ++ii) {
      const int i = wv * 2 + ii;                 // 0..15
      const int r = 2 * i + (l >> 5);            // 0..31
      const char* src = wnb + (size_t)(o0 + r) * 512 + (((l & 31) ^ (r & 7)) << 4);
      __builtin_amdgcn_global_load_lds((gvoid_t*)src,
                                       (svoid_t*)(NL + i * 1024 + l * 16), 16, 0, 0);
    }
  }
  FENCE();

  // chunk x-slab: [m-row][1024B], 32B-granule swizzle key m&7; 2 instr/wave
#define STAGE_X(c, buf) { \
    _Pragma("unroll") \
    for (int jj = 0; jj < 2; ++jj) { \
      const int j = wv * 2 + jj; \
      const char* src = xb + (size_t)j * 16384 + (size_t)(c) * 1024 \
                        + ((((l >> 1) ^ (j & 7)) << 5) | ((l & 1) << 4)); \
      __builtin_amdgcn_global_load_lds((gvoid_t*)src, \
                                       (svoid_t*)((buf) + j * 1024 + l * 16), 16, 0, 0); \
    } }

  // chunk W-slab: [r][256B] r in [0,32), 16B-granule swizzle r&7; 1 instr/wave
#define STAGE_W(c, buf) { \
    const int r = wv * 4 + (l >> 4); \
    const char* src = wqb + (size_t)(o0 + r) * 4096 + (size_t)(c) * 256 \
                      + (((l & 15) ^ (r & 7)) << 4); \
    __builtin_amdgcn_global_load_lds((gvoid_t*)src, \
                                     (svoid_t*)((buf) + wv * 1024 + l * 16), 16, 0, 0); }

  STAGE_X(0, X0); STAGE_W(0, W0); FENCE();
  STAGE_X(1, X1); STAGE_W(1, W1); FENCE();
  // per-wave outstanding: norms(2) + S0(3) + S1(3) = 8

  // ---- LUT build on VALU while DMAs fly
  {
    USH h0, h1, h2, h3;
    h0.h = __float2half(-1.0f);  h1.h = __float2half(-0.333f);
    h2.h = __float2half(0.333f); h3.h = __float2half(1.0f);
    const uint hv[4] = {h0.s, h1.s, h2.s, h3.s};
#pragma unroll
    for (int e = 0; e < 4; ++e) {
      const int idx = e * 64 + l;
      const uint lo = hv[idx & 3]        | (hv[(idx >> 2) & 3] << 16);
      const uint hi = hv[(idx >> 4) & 3] | (hv[(idx >> 6) & 3] << 16);
      *(uint2*)(LUT + idx * 8) = make_uint2(lo, hi);
    }
  }

  f32x4 acc = {0.f, 0.f, 0.f, 0.f};
  const int c7  = col & 7;           // ol&7 == col&7 (ol = oh*16+col, 16 = 0 mod 8)
  const int ol  = oh * 16 + col;     // o-row within the 32-row tile

#define COMPUTE(c, xs, ws) { \
    const float2 nn = *(const float2*)(NL + ol * 512 \
                        + ((((c) * 2 + (kq >> 1)) ^ c7) << 4) + (kq & 1) * 8); \
    _Pragma("unroll") \
    for (int jj = 0; jj < 2; ++jj) { \
      const int lg = kq * 2 + jj; \
      const float nv = jj ? nn.y : nn.x; \
      UH nvh; nvh.h = __floats2half2_rn(nv, nv); \
      const uint2 p = *(const uint2*)((ws) + ol * 256 \
                        + (((lg * 2 + (q >> 1)) ^ c7) << 4) + (q & 1) * 8); \
      const int xaddr = col * 1024 + (((lg * 4 + q) ^ c7) << 5); \
      const float4 xa = *(const float4*)((xs) + xaddr); \
      const float4 xc = *(const float4*)((xs) + xaddr + 16); \
      UH k0, k1, k2, k3; \
      k0.h = __floats2half2_rn(xa.x, xa.y); k1.h = __floats2half2_rn(xa.z, xa.w); \
      k2.h = __floats2half2_rn(xc.x, xc.y); k3.h = __floats2half2_rn(xc.z, xc.w); \
      UA A; A.u[0] = k0.u; A.u[1] = k1.u; A.u[2] = k2.u; A.u[3] = k3.u; \
      const uint2 e0 = *(const uint2*)(LUT + ((size_t)(uint)p.x << 3)); \
      const uint2 e1 = *(const uint2*)(LUT + ((size_t)(uint)p.y << 3)); \
      UH a0, a1, a2, a3, b0, b1, b2, b3; \
      a0.u = e0.x; a1.u = e0.y; a2.u = e1.x; a3.u = e1.y; \
      b0.h = __hmul2(a0.h, nvh.h); b1.h = __hmul2(a1.h, nvh.h); \
      b2.h = __hmul2(a2.h, nvh.h); b3.h = __hmul2(a3.h, nvh.h); \
      UA B; B.u[0] = b0.u; B.u[1] = b1.u; B.u[2] = b2.u; B.u[3] = b3.u; \
      acc = __builtin_amdgcn_mfma_f32_16x16x32_f16(A.v, B.v, acc, 0, 0, 0); \
    } }

#define ITER_FULL(c, XS, WS) \
  WAITV(3); BARRIER(); \
  COMPUTE(c, XS, WS) \
  BARRIER(); \
  STAGE_X((c) + 2, XS); STAGE_W((c) + 2, WS); FENCE();

  ITER_FULL(0,  X0, W0)  ITER_FULL(1,  X1, W1)
  ITER_FULL(2,  X0, W0)  ITER_FULL(3,  X1, W1)
  ITER_FULL(4,  X0, W0)  ITER_FULL(5,  X1, W1)
  ITER_FULL(6,  X0, W0)  ITER_FULL(7,  X1, W1)
  ITER_FULL(8,  X0, W0)  ITER_FULL(9,  X1, W1)
  ITER_FULL(10, X0, W0)  ITER_FULL(11, X1, W1)
  ITER_FULL(12, X0, W0)  ITER_FULL(13, X1, W1)
  WAITV(3); BARRIER(); COMPUTE(14, X0, W0)
  WAITV(0); BARRIER(); COMPUTE(15, X1, W1)
#undef ITER_FULL
#undef COMPUTE
#undef STAGE_X
#undef STAGE_W

  // ---- cross-wave reduction over kq (overlay on LUT+NL region) + bias + store
  __syncthreads();
  float* red = (float*)lds;          // 8 waves x 256 floats = 8 KB
  red[wv * 256 +   0 + l] = acc[0];
  red[wv * 256 +  64 + l] = acc[1];
  red[wv * 256 + 128 + l] = acc[2];
  red[wv * 256 + 192 + l] = acc[3];
  __syncthreads();
  const int t = tid;                 // 512 outputs: (oh2, i, l2)
  const int oh2 = t >> 8;
  const int r2  = t & 255;
  float s = red[(0 * 2 + oh2) * 256 + r2] + red[(1 * 2 + oh2) * 256 + r2]
          + red[(2 * 2 + oh2) * 256 + r2] + red[(3 * 2 + oh2) * 256 + r2];
  const int i2 = r2 >> 6, l2 = r2 & 63;
  const int m  = ((l2 >> 4) << 2) + i2;      // D row = (lane>>4)*4 + reg
  const int oc = o0 + oh2 * 16 + (l2 & 15);  // D col
  out[(size_t)m * OUTF + oc] = s + bias[oc];
}

extern "C" void kernel_launch(void* const* d_in, const int* in_sizes, int n_in,
                              void* d_out, int out_size, void* d_ws, size_t ws_size,
                              hipStream_t stream) {
  (void)in_sizes; (void)n_in; (void)out_size; (void)d_ws; (void)ws_size;
  const float* x    = (const float*)d_in[0];
  const int*   wq   = (const int*)d_in[1];
  const float* wn   = (const float*)d_in[2];
  const float* bias = (const float*)d_in[3];
  float*       out  = (float*)d_out;
  lin2bit_kernel<<<dim3(NBLK), dim3(512), 0, stream>>>(x, wq, wn, bias, out);
}